// Round 2
// baseline (20064.761 us; speedup 1.0000x reference)
//
#include <hip/hip_runtime.h>
#include <math.h>

// LSTM: T=512, B=64, E=1024, H=1024. fp32 correctness-first baseline.
// One kernel launch per timestep (kernel boundary = global barrier).
// Each step: z[16 rows x 64 b] per block over fused K=2048 ([w_h | w_x] vs [h | x]),
// then gates + c/h update fused in the epilogue.
//
// R2 change vs R1: lane->batch mapping in the compute loop is strided
// (lane q owns batches {q, q+16, q+32, q+48}) instead of consecutive
// ({4q..4q+3}), turning the V-tile ds_read_b128 pattern from ~8-way bank
// conflict into 2-way (free). Epilogue gather index updated to match.

#define T_STEPS 512
#define BATCH   64
#define EMB     1024
#define HID     1024
#define KTOT    2048      // fused K: 1024 (h) + 1024 (x)
#define KT      128       // K tile
#define NTILES  16        // KTOT / KT
#define HTILES  8         // tiles belonging to the h-part (1024/128)
#define THREADS 512
#define NU      4         // hidden units per block
#define NBLK    (HID / NU)   // 256 blocks

__device__ __forceinline__ float sigf(float x) {
    return 1.0f / (1.0f + __expf(-x));
}
__device__ __forceinline__ float tanhf_fast(float x) {
    // tanh(x) = 1 - 2/(exp(2x)+1); saturates correctly at +/-inf
    return 1.0f - 2.0f / (__expf(2.0f * x) + 1.0f);
}

__global__ __launch_bounds__(THREADS)
void lstm_step(const float* __restrict__ embeds,  // [T][B][E]
               const float* __restrict__ w_x,     // [4H][E]
               const float* __restrict__ w_h,     // [4H][H]
               const float* __restrict__ b_i,
               const float* __restrict__ b_f,
               const float* __restrict__ b_o,
               const float* __restrict__ b_g,
               float* __restrict__ out,           // [T][B][H]; h_t written to row t
               float* __restrict__ c_buf,         // [B][H] running cell state (ws)
               int t)
{
    // +4 float pad: keeps ds_read_b128 16B-aligned (row stride 528 B)
    __shared__ float xt[BATCH][KT + 4];   // V tile: [b][k]   (h or x)
    __shared__ float wt[16][KT + 4];      // W tile: [row][k] (16 gate-rows of this block)
    __shared__ float red[THREADS * 16];   // split-K partials

    const int tid = threadIdx.x;
    const int n0  = blockIdx.x * NU;      // first hidden unit owned by this block

    const float* h_prev = out + (size_t)(t - 1) * BATCH * HID;   // only deref'd if t>0
    const float* x_t    = embeds + (size_t)t * BATCH * EMB;

    // compute-thread mapping: wave id = split-K group;
    // lane: gate = wv>>4 (rows 4g..4g+3), q = wv&15 owns batches {q,q+16,q+32,q+48}
    const int wv = tid & 63;
    const int kg = tid >> 6;              // 0..7 (k-slice within each tile)
    const int r0 = (wv >> 4) << 2;        // {0,4,8,12}
    const int q  = wv & 15;               // batch lane

    float4 acc[4];
    #pragma unroll
    for (int i = 0; i < 4; ++i) acc[i] = make_float4(0.f, 0.f, 0.f, 0.f);

    const int tile0 = (t == 0) ? HTILES : 0;   // t==0: h == 0, skip h-part entirely

    for (int tile = tile0; tile < NTILES; ++tile) {
        const int kbase = tile * KT;               // 0..2047
        const bool hpart = (kbase < HID);
        // offset by -HID so kbase indexes both halves uniformly
        const float* Vsrc = hpart ? h_prev : (x_t - HID);
        const float* Wsrc = hpart ? w_h    : (w_x - HID);

        // ---- stage V tile: xt[b][k], 64 b x 128 k; thread: b = tid/8, 16 k's ----
        {
            const int b  = tid >> 3;
            const int k0 = (tid & 7) << 4;
            const float4* src = (const float4*)(Vsrc + (size_t)b * 1024 + kbase + k0);
            float4 v0 = src[0], v1 = src[1], v2 = src[2], v3 = src[3];
            float4* dst = (float4*)&xt[b][k0];
            dst[0] = v0; dst[1] = v1; dst[2] = v2; dst[3] = v3;
        }
        // ---- stage W tile: wt[r][k], 16 rows x 128 k; thread: r = tid/32, 4 k's ----
        {
            const int r    = tid >> 5;
            const int k0   = (tid & 31) << 2;
            const int grow = ((r >> 2) * HID) + n0 + (r & 3);  // gate*H + n0 + unit
            float4 v = *(const float4*)(Wsrc + (size_t)grow * 1024 + kbase + k0);
            *(float4*)&wt[r][k0] = v;
        }
        __syncthreads();

        // ---- compute this wave's 16-k slice of the tile ----
        const int ks = kg << 4;
        #pragma unroll
        for (int kk = 0; kk < 16; kk += 4) {
            float4 xv[4], wq[4];
            #pragma unroll
            for (int i = 0; i < 4; ++i) xv[i] = *(const float4*)&xt[q + (i << 4)][ks + kk];
            #pragma unroll
            for (int i = 0; i < 4; ++i) wq[i] = *(const float4*)&wt[r0 + i][ks + kk];
            #pragma unroll
            for (int ri = 0; ri < 4; ++ri) {
                // acc[ri].{x,y,z,w} = batches {q, q+16, q+32, q+48}, row r0+ri
                acc[ri].x = fmaf(wq[ri].x, xv[0].x, acc[ri].x);
                acc[ri].x = fmaf(wq[ri].y, xv[0].y, acc[ri].x);
                acc[ri].x = fmaf(wq[ri].z, xv[0].z, acc[ri].x);
                acc[ri].x = fmaf(wq[ri].w, xv[0].w, acc[ri].x);
                acc[ri].y = fmaf(wq[ri].x, xv[1].x, acc[ri].y);
                acc[ri].y = fmaf(wq[ri].y, xv[1].y, acc[ri].y);
                acc[ri].y = fmaf(wq[ri].z, xv[1].z, acc[ri].y);
                acc[ri].y = fmaf(wq[ri].w, xv[1].w, acc[ri].y);
                acc[ri].z = fmaf(wq[ri].x, xv[2].x, acc[ri].z);
                acc[ri].z = fmaf(wq[ri].y, xv[2].y, acc[ri].z);
                acc[ri].z = fmaf(wq[ri].z, xv[2].z, acc[ri].z);
                acc[ri].z = fmaf(wq[ri].w, xv[2].w, acc[ri].z);
                acc[ri].w = fmaf(wq[ri].x, xv[3].x, acc[ri].w);
                acc[ri].w = fmaf(wq[ri].y, xv[3].y, acc[ri].w);
                acc[ri].w = fmaf(wq[ri].z, xv[3].z, acc[ri].w);
                acc[ri].w = fmaf(wq[ri].w, xv[3].w, acc[ri].w);
            }
        }
        __syncthreads();
    }

    // ---- split-K reduction + gates + state update ----
    {
        float4* red4 = (float4*)red;
        #pragma unroll
        for (int ri = 0; ri < 4; ++ri) red4[tid * 4 + ri] = acc[ri];
    }
    __syncthreads();

    if (tid < NU * BATCH) {               // 256 threads, one (unit, batch) each
        const int u = tid & 3;
        const int b = tid >> 2;
        const int n = n0 + u;

        float z[4];
        #pragma unroll
        for (int g = 0; g < 4; ++g) {
            float s = 0.f;
            #pragma unroll
            for (int kgi = 0; kgi < 8; ++kgi) {
                // owner lane: wv = g*16 + (b&15); acc[u] component (b>>4)
                s += red[((kgi << 6) + (g << 4) + (b & 15)) * 16 + (u << 2) + (b >> 4)];
            }
            z[g] = s;
        }

        const float ig = sigf(z[0] + b_i[n]);
        const float fg = sigf(z[1] + b_f[n]);
        const float og = sigf(z[2] + b_o[n]);
        const float gg = tanhf_fast(z[3] + b_g[n]);

        const float cold = (t == 0) ? 0.f : c_buf[b * HID + n];
        const float cn   = fmaf(gg, ig, cold * fg);
        c_buf[b * HID + n] = cn;
        out[(size_t)t * BATCH * HID + b * HID + n] = tanhf_fast(cn) * og;
    }
}

extern "C" void kernel_launch(void* const* d_in, const int* in_sizes, int n_in,
                              void* d_out, int out_size, void* d_ws, size_t ws_size,
                              hipStream_t stream) {
    (void)in_sizes; (void)n_in; (void)out_size; (void)ws_size;

    const float* embeds = (const float*)d_in[0];
    const float* w_x    = (const float*)d_in[1];
    const float* w_h    = (const float*)d_in[2];
    const float* b_i    = (const float*)d_in[3];
    const float* b_f    = (const float*)d_in[4];
    const float* b_o    = (const float*)d_in[5];
    const float* b_g    = (const float*)d_in[6];

    float* out   = (float*)d_out;
    float* c_buf = (float*)d_ws;          // [B][H] fp32 = 256 KB

    for (int t = 0; t < T_STEPS; ++t) {
        hipLaunchKernelGGL(lstm_step, dim3(NBLK), dim3(THREADS), 0, stream,
                           embeds, w_x, w_h, b_i, b_f, b_o, b_g, out, c_buf, t);
    }
}

// Round 4
// 7871.653 us; speedup vs baseline: 2.5490x; 2.5490x over previous
//
#include <hip/hip_runtime.h>
#include <math.h>

// LSTM T=512, B=64, E=1024, H=1024.
// Primary path: bf16 MFMA (one launch per timestep, weights pre-packed to bf16
// in ws). Fallback path (ws too small): proven fp32 VALU kernel from R2.
//
// R4 change vs R3: kernel_launch checks ws_size before using the 16.5 MB
// w_cat layout — rules out ws-OOB as a container-killer. Branch is on a
// launch-constant => identical work every call (graph-capture safe).

#define T_STEPS 512
#define BATCH   64
#define EMB     1024
#define HID     1024

typedef __attribute__((ext_vector_type(8)))  short short8;
typedef __attribute__((ext_vector_type(16))) float f32x16;

__device__ __forceinline__ unsigned short f2bf(float f) {
    unsigned int u = __float_as_uint(f);
    u = (u + 0x7fffu + ((u >> 16) & 1u)) >> 16;   // round-to-nearest-even
    return (unsigned short)u;
}
__device__ __forceinline__ float sigf(float x) { return 1.0f / (1.0f + __expf(-x)); }
__device__ __forceinline__ float tanh_fast(float x) {
    return 1.0f - 2.0f / (__expf(2.0f * x) + 1.0f);   // saturates correctly
}

// ===================== bf16 MFMA path =====================
// ws layout: w_cat bf16 [4096][2048] | h_bf bf16 [2][64][1024] | c fp32 [64][1024]
#define WCAT_BYTES (4096ull * 2048ull * 2ull)
#define HBF_BYTES  (2ull * 64ull * 1024ull * 2ull)
#define C_BYTES    (64ull * 1024ull * 4ull)
#define WS_NEEDED  (WCAT_BYTES + HBF_BYTES + C_BYTES)

// Pack [w_h | w_x] rows into block-permuted bf16 layout:
// storage row p = blk*32 + g*8 + u  where n = blk*8 + u, source row = g*1024 + n.
__global__ __launch_bounds__(256)
void convert_weights(const float* __restrict__ w_x,
                     const float* __restrict__ w_h,
                     short* __restrict__ w_cat)
{
    const int gid = blockIdx.x * 256 + threadIdx.x;   // 4096 blocks * 256 threads
    const int p   = gid >> 8;
    const int k   = (gid & 255) * 8;
    const int blk = p >> 5, r = p & 31;
    const int g = r >> 3, u = r & 7;
    const int srow = g * 1024 + blk * 8 + u;
    const float* src = (k < 1024) ? (w_h + (size_t)srow * 1024 + k)
                                  : (w_x + (size_t)srow * 1024 + (k - 1024));
    float4 f0 = ((const float4*)src)[0];
    float4 f1 = ((const float4*)src)[1];
    short8 v;
    v[0] = (short)f2bf(f0.x); v[1] = (short)f2bf(f0.y);
    v[2] = (short)f2bf(f0.z); v[3] = (short)f2bf(f0.w);
    v[4] = (short)f2bf(f1.x); v[5] = (short)f2bf(f1.y);
    v[6] = (short)f2bf(f1.z); v[7] = (short)f2bf(f1.w);
    *(short8*)(w_cat + (size_t)p * 2048 + k) = v;
}

__global__ __launch_bounds__(256)
void lstm_step(const float* __restrict__ embeds,   // [T][B][E] fp32
               const short* __restrict__ w_cat,    // [4096][2048] bf16 (permuted)
               const float* __restrict__ b_i, const float* __restrict__ b_f,
               const float* __restrict__ b_o, const float* __restrict__ b_g,
               float* __restrict__ out,            // [T][B][H] fp32
               short* __restrict__ h_bf,           // [2][64][1024] bf16
               float* __restrict__ c_buf,          // [64][1024] fp32
               int t)
{
    __shared__ __align__(16) short vt[32 * 512];     // v tile (batch half), swizzled
    __shared__ __align__(16) short wt[32 * 512];     // W strip chunk, swizzled
    __shared__ float red[4][32][33];                 // split-K partials (+1 pad)

    const int tid = threadIdx.x;
    const int Rt  = blockIdx.x >> 1;       // row-tile 0..127 (8 units each)
    const int bh  = blockIdx.x & 1;        // batch half
    const int wv  = tid >> 6;              // wave 0..3
    const int l   = tid & 63;

    const short* hprev = h_bf + ((t + 1) & 1) * (64 * 1024);
    const float* xt    = embeds + (size_t)t * BATCH * EMB;

    f32x16 acc = {};

    const int s0 = (t == 0) ? 2 : 0;       // t==0: h==0, skip h-half chunks
    for (int s = s0; s < 4; ++s) {
        const int kb = 512 * s;            // fused-k base of this chunk
        // ---- stage vt: 32 batches x 512 k ----
        if (kb < 1024) {                   // h part: bf16 source
            #pragma unroll
            for (int j = 0; j < 8; ++j) {
                const int fid = j * 256 + tid;
                const int b   = fid >> 6;
                const int k   = (fid & 63) * 8;
                short8 v = *(const short8*)(hprev + (size_t)(bh * 32 + b) * 1024 + kb + k);
                *(short8*)((char*)vt + b * 1024 + ((k * 2) ^ ((b & 7) << 4))) = v;
            }
        } else {                           // x part: fp32 source, convert
            #pragma unroll
            for (int j = 0; j < 8; ++j) {
                const int fid = j * 256 + tid;
                const int b   = fid >> 6;
                const int k   = (fid & 63) * 8;
                const float* sp = xt + (size_t)(bh * 32 + b) * 1024 + (kb - 1024) + k;
                float4 f0 = ((const float4*)sp)[0];
                float4 f1 = ((const float4*)sp)[1];
                short8 v;
                v[0] = (short)f2bf(f0.x); v[1] = (short)f2bf(f0.y);
                v[2] = (short)f2bf(f0.z); v[3] = (short)f2bf(f0.w);
                v[4] = (short)f2bf(f1.x); v[5] = (short)f2bf(f1.y);
                v[6] = (short)f2bf(f1.z); v[7] = (short)f2bf(f1.w);
                *(short8*)((char*)vt + b * 1024 + ((k * 2) ^ ((b & 7) << 4))) = v;
            }
        }
        // ---- stage wt: 32 rows x 512 k ----
        #pragma unroll
        for (int j = 0; j < 8; ++j) {
            const int fid = j * 256 + tid;
            const int r   = fid >> 6;
            const int k   = (fid & 63) * 8;
            short8 v = *(const short8*)(w_cat + (size_t)(Rt * 32 + r) * 2048 + kb + k);
            *(short8*)((char*)wt + r * 1024 + ((k * 2) ^ ((r & 7) << 4))) = v;
        }
        __syncthreads();

        // ---- compute: wave wv -> k-slice [128*wv, +128); 8 MFMA ----
        {
            const int row = l & 31;                  // A row / B col lane index
            const int kh  = (l >> 5) << 3;           // 0 or 8
            const int swz = (row & 7) << 4;
            #pragma unroll
            for (int kk = 0; kk < 128; kk += 16) {
                const int kl = 128 * wv + kk + kh;
                short8 a = *(const short8*)((const char*)wt + row * 1024 + ((kl * 2) ^ swz));
                short8 b = *(const short8*)((const char*)vt + row * 1024 + ((kl * 2) ^ swz));
                acc = __builtin_amdgcn_mfma_f32_32x32x16_bf16(a, b, acc, 0, 0, 0);
            }
        }
        __syncthreads();
    }

    // ---- split-K partials: D col = l&31, row = (reg&3)+8*(reg>>2)+4*(l>>5) ----
    {
        const int col = l & 31;
        #pragma unroll
        for (int reg = 0; reg < 16; ++reg) {
            const int rr = (reg & 3) + ((reg >> 2) << 3) + ((l >> 5) << 2);
            red[wv][rr][col] = acc[reg];
        }
    }
    __syncthreads();

    // ---- epilogue: 256 outputs = 8 units x 32 batches ----
    {
        const int u    = tid & 7;
        const int bloc = tid >> 3;
        const int b    = bh * 32 + bloc;
        const int n    = Rt * 8 + u;

        float z[4];
        #pragma unroll
        for (int g = 0; g < 4; ++g) {
            const int rr = g * 8 + u;
            z[g] = red[0][rr][bloc] + red[1][rr][bloc] +
                   red[2][rr][bloc] + red[3][rr][bloc];
        }
        const float ig = sigf(z[0] + b_i[n]);
        const float fg = sigf(z[1] + b_f[n]);
        const float og = sigf(z[2] + b_o[n]);
        const float gg = tanh_fast(z[3] + b_g[n]);

        const float cold = (t == 0) ? 0.0f : c_buf[b * 1024 + n];
        const float cn   = fmaf(gg, ig, cold * fg);
        c_buf[b * 1024 + n] = cn;
        const float h = tanh_fast(cn) * og;
        out[(size_t)t * (BATCH * HID) + b * 1024 + n] = h;
        h_bf[(t & 1) * (64 * 1024) + b * 1024 + n] = (short)f2bf(h);
    }
}

// ===================== fp32 fallback path (R2, proven) =====================
#define KT      128
#define NTILES  16
#define HTILES  8
#define THREADS 512
#define NU      4
#define NBLK    (HID / NU)

__global__ __launch_bounds__(THREADS)
void lstm_step_fp32(const float* __restrict__ embeds,
                    const float* __restrict__ w_x,
                    const float* __restrict__ w_h,
                    const float* __restrict__ b_i,
                    const float* __restrict__ b_f,
                    const float* __restrict__ b_o,
                    const float* __restrict__ b_g,
                    float* __restrict__ out,
                    float* __restrict__ c_buf,
                    int t)
{
    __shared__ float xt[BATCH][KT + 4];
    __shared__ float wt[16][KT + 4];
    __shared__ float red[THREADS * 16];

    const int tid = threadIdx.x;
    const int n0  = blockIdx.x * NU;

    const float* h_prev = out + (size_t)(t - 1) * BATCH * HID;
    const float* x_t    = embeds + (size_t)t * BATCH * EMB;

    const int wv = tid & 63;
    const int kg = tid >> 6;
    const int r0 = (wv >> 4) << 2;
    const int q  = wv & 15;

    float4 acc[4];
    #pragma unroll
    for (int i = 0; i < 4; ++i) acc[i] = make_float4(0.f, 0.f, 0.f, 0.f);

    const int tile0 = (t == 0) ? HTILES : 0;

    for (int tile = tile0; tile < NTILES; ++tile) {
        const int kbase = tile * KT;
        const bool hpart = (kbase < HID);
        const float* Vsrc = hpart ? h_prev : (x_t - HID);
        const float* Wsrc = hpart ? w_h    : (w_x - HID);

        {
            const int b  = tid >> 3;
            const int k0 = (tid & 7) << 4;
            const float4* src = (const float4*)(Vsrc + (size_t)b * 1024 + kbase + k0);
            float4 v0 = src[0], v1 = src[1], v2 = src[2], v3 = src[3];
            float4* dst = (float4*)&xt[b][k0];
            dst[0] = v0; dst[1] = v1; dst[2] = v2; dst[3] = v3;
        }
        {
            const int r    = tid >> 5;
            const int k0   = (tid & 31) << 2;
            const int grow = ((r >> 2) * HID) + n0 + (r & 3);
            float4 v = *(const float4*)(Wsrc + (size_t)grow * 1024 + kbase + k0);
            *(float4*)&wt[r][k0] = v;
        }
        __syncthreads();

        const int ks = kg << 4;
        #pragma unroll
        for (int kk = 0; kk < 16; kk += 4) {
            float4 xv[4], wq[4];
            #pragma unroll
            for (int i = 0; i < 4; ++i) xv[i] = *(const float4*)&xt[q + (i << 4)][ks + kk];
            #pragma unroll
            for (int i = 0; i < 4; ++i) wq[i] = *(const float4*)&wt[r0 + i][ks + kk];
            #pragma unroll
            for (int ri = 0; ri < 4; ++ri) {
                acc[ri].x = fmaf(wq[ri].x, xv[0].x, acc[ri].x);
                acc[ri].x = fmaf(wq[ri].y, xv[0].y, acc[ri].x);
                acc[ri].x = fmaf(wq[ri].z, xv[0].z, acc[ri].x);
                acc[ri].x = fmaf(wq[ri].w, xv[0].w, acc[ri].x);
                acc[ri].y = fmaf(wq[ri].x, xv[1].x, acc[ri].y);
                acc[ri].y = fmaf(wq[ri].y, xv[1].y, acc[ri].y);
                acc[ri].y = fmaf(wq[ri].z, xv[1].z, acc[ri].y);
                acc[ri].y = fmaf(wq[ri].w, xv[1].w, acc[ri].y);
                acc[ri].z = fmaf(wq[ri].x, xv[2].x, acc[ri].z);
                acc[ri].z = fmaf(wq[ri].y, xv[2].y, acc[ri].z);
                acc[ri].z = fmaf(wq[ri].z, xv[2].z, acc[ri].z);
                acc[ri].z = fmaf(wq[ri].w, xv[2].w, acc[ri].z);
                acc[ri].w = fmaf(wq[ri].x, xv[3].x, acc[ri].w);
                acc[ri].w = fmaf(wq[ri].y, xv[3].y, acc[ri].w);
                acc[ri].w = fmaf(wq[ri].z, xv[3].z, acc[ri].w);
                acc[ri].w = fmaf(wq[ri].w, xv[3].w, acc[ri].w);
            }
        }
        __syncthreads();
    }

    {
        float4* red4 = (float4*)red;
        #pragma unroll
        for (int ri = 0; ri < 4; ++ri) red4[tid * 4 + ri] = acc[ri];
    }
    __syncthreads();

    if (tid < NU * BATCH) {
        const int u = tid & 3;
        const int b = tid >> 2;
        const int n = n0 + u;

        float z[4];
        #pragma unroll
        for (int g = 0; g < 4; ++g) {
            float s = 0.f;
            #pragma unroll
            for (int kgi = 0; kgi < 8; ++kgi) {
                s += red[((kgi << 6) + (g << 4) + (b & 15)) * 16 + (u << 2) + (b >> 4)];
            }
            z[g] = s;
        }

        const float ig = sigf(z[0] + b_i[n]);
        const float fg = sigf(z[1] + b_f[n]);
        const float og = sigf(z[2] + b_o[n]);
        const float gg = tanh_fast(z[3] + b_g[n]);

        const float cold = (t == 0) ? 0.f : c_buf[b * HID + n];
        const float cn   = fmaf(gg, ig, cold * fg);
        c_buf[b * HID + n] = cn;
        out[(size_t)t * BATCH * HID + b * HID + n] = tanh_fast(cn) * og;
    }
}

// ===================== launcher =====================
extern "C" void kernel_launch(void* const* d_in, const int* in_sizes, int n_in,
                              void* d_out, int out_size, void* d_ws, size_t ws_size,
                              hipStream_t stream) {
    (void)in_sizes; (void)n_in; (void)out_size;

    const float* embeds = (const float*)d_in[0];
    const float* w_x    = (const float*)d_in[1];
    const float* w_h    = (const float*)d_in[2];
    const float* b_i    = (const float*)d_in[3];
    const float* b_f    = (const float*)d_in[4];
    const float* b_o    = (const float*)d_in[5];
    const float* b_g    = (const float*)d_in[6];

    float* out = (float*)d_out;

    if (ws_size >= WS_NEEDED) {
        // bf16 MFMA path
        char*  ws    = (char*)d_ws;
        short* w_cat = (short*)ws;
        short* h_bf  = (short*)(ws + WCAT_BYTES);
        float* c_buf = (float*)(ws + WCAT_BYTES + HBF_BYTES);

        hipLaunchKernelGGL(convert_weights, dim3(4096), dim3(256), 0, stream,
                           w_x, w_h, w_cat);
        for (int t = 0; t < T_STEPS; ++t) {
            hipLaunchKernelGGL(lstm_step, dim3(256), dim3(256), 0, stream,
                               embeds, w_cat, b_i, b_f, b_o, b_g, out, h_bf, c_buf, t);
        }
    } else {
        // fp32 fallback (needs only 256 KB of ws)
        float* c_buf = (float*)d_ws;
        for (int t = 0; t < T_STEPS; ++t) {
            hipLaunchKernelGGL(lstm_step_fp32, dim3(NBLK), dim3(THREADS), 0, stream,
                               embeds, w_x, w_h, b_i, b_f, b_o, b_g, out, c_buf, t);
        }
    }
}